// Round 4
// baseline (384.523 us; speedup 1.0000x reference)
//
#include <hip/hip_runtime.h>

#define BB 64
#define DD 512
#define DINN 512
#define MM 32
#define HH 64
#define DSQ (DD*DD)

// ---------------- persistent device scratch (no d_ws dependence) ----------------
__device__ float g_state[BB * DD];
__device__ float g_act[BB * DD];
__device__ float g_w1at[(size_t)MM * 2 * HH * DD];   // 8 MB fp32 transposed w1a
__device__ float g_part[BB * 64 * 2];                // per (row, blk) partial sum/sumsq
__device__ float g_wfpart[64];                       // per-block partial ||Wfix||^2

// ---------------- helpers ----------------
__device__ __forceinline__ float wave_sum(float v) {
#pragma unroll
  for (int m = 32; m; m >>= 1) v += __shfl_xor(v, m);
  return v;
}
__device__ __forceinline__ float sigmoidf_(float x) {
  return 1.f / (1.f + __expf(-x));
}
__device__ __forceinline__ float r_elem(float p, float al, float be, float pw) {
  float c  = fminf(fmaxf(p, 0.f), 15.f);
  float w2 = __expf(-2.f * c);           // dw^2 = exp(-clip)^2
  return (w2 * al + pw) * rsqrtf(w2 * be + 1.f);
}

// ---------------- K0: ||weights_fixed||_F^2 partials ----------------
__global__ __launch_bounds__(256) void k_wfnorm(const float* __restrict__ wf) {
  int tid = blockIdx.x * 256 + threadIdx.x;
  const float4* w4 = (const float4*)wf;
  float s = 0.f;
  for (int i = tid; i < DSQ / 4; i += 64 * 256) {
    float4 v = w4[i];
    s += v.x * v.x + v.y * v.y + v.z * v.z + v.w * v.w;
  }
  s = wave_sum(s);
  __shared__ float red[4];
  int wave = threadIdx.x >> 6, lane = threadIdx.x & 63;
  if (lane == 0) red[wave] = s;
  __syncthreads();
  if (threadIdx.x == 0) g_wfpart[blockIdx.x] = red[0] + red[1] + red[2] + red[3];
}

// ------- K_t: transpose w1a (4096 x 512) -> g_w1at (512 x 4096) -------
__global__ __launch_bounds__(256) void k_transpose(const float* __restrict__ A) {
  __shared__ float tile[32][33];
  int c0 = blockIdx.x * 32;          // d
  int r0 = blockIdx.y * 32;          // m*128+l
  int tx = threadIdx.x & 31, ty = threadIdx.x >> 5;   // 32 x 8
#pragma unroll
  for (int i = 0; i < 32; i += 8)
    tile[ty + i][tx] = A[(size_t)(r0 + ty + i) * DD + c0 + tx];
  __syncthreads();
#pragma unroll
  for (int i = 0; i < 32; i += 8)
    g_w1at[(size_t)(c0 + ty + i) * 4096 + r0 + tx] = tile[tx][ty + i];
}

// ---- K2: y = inp@Wp.T + bp ; t = y@(Wfix/||Wfix||) ; state = LN_D(t) ----
__global__ __launch_bounds__(512) void k_state(
    const float* __restrict__ x, const float* __restrict__ post,
    const float* __restrict__ Wp, const float* __restrict__ bp,
    const float* __restrict__ Wfix, const float* __restrict__ lng,
    const float* __restrict__ lnb) {
  __shared__ float inp[DINN + DD];
  __shared__ float yrow[DD];
  __shared__ float red[16];
  const int b = blockIdx.x;
  const int t = threadIdx.x;
  inp[t]        = x[(size_t)b * DINN + t];
  inp[DINN + t] = post[(size_t)b * DD * MM + (size_t)t * MM + (MM - 1)];
  __syncthreads();
  float acc = bp[t];
  const float4* wrow = (const float4*)(Wp + (size_t)t * (DINN + DD));
#pragma unroll 4
  for (int k = 0; k < (DINN + DD) / 4; ++k) {
    float4 w = wrow[k];
    acc += inp[4*k]*w.x + inp[4*k+1]*w.y + inp[4*k+2]*w.z + inp[4*k+3]*w.w;
  }
  yrow[t] = acc;
  __syncthreads();
  float wf2 = 0.f;
#pragma unroll
  for (int i = 0; i < 64; ++i) wf2 += g_wfpart[i];
  float tv = 0.f;
#pragma unroll 4
  for (int dd2 = 0; dd2 < DD; ++dd2)
    tv = fmaf(yrow[dd2], Wfix[(size_t)dd2 * DD + t], tv);
  tv *= rsqrtf(wf2);                            // / ||weights_fixed||_F
  // LayerNorm over the 512 threads
  int wave = t >> 6, lane = t & 63;
  float v = wave_sum(tv);
  if (lane == 0) red[wave] = v;
  __syncthreads();
  float tot = 0.f;
#pragma unroll
  for (int i = 0; i < 8; ++i) tot += red[i];
  float mu = tot * (1.f / 512.f);
  float dv = tv - mu;
  float v2 = wave_sum(dv * dv);
  if (lane == 0) red[8 + wave] = v2;
  __syncthreads();
  float tot2 = 0.f;
#pragma unroll
  for (int i = 0; i < 8; ++i) tot2 += red[8 + i];
  float rstd = rsqrtf(tot2 * (1.f / 512.f) + 1e-5f);
  g_state[b * DD + t] = dv * rstd * lng[t] + lnb[t];
}

// ---- K3: h einsum + GLU + LN(H) + o einsum + GLU -> g_act ----
__global__ __launch_bounds__(256) void k_act(
    const float* __restrict__ pre, const float* __restrict__ b1a,
    const float* __restrict__ lng, const float* __restrict__ lnb,
    const float* __restrict__ w1b, const float* __restrict__ b1b) {
  __shared__ float W[MM * 2 * HH];      // [m][l]  (32 x 128)
  __shared__ float st[BB][MM + 1];
  __shared__ float wb[2 * HH];
  __shared__ float ba[2 * HH];
  const int d = blockIdx.x;
  const int t = threadIdx.x;
  {
    const float* Wg = g_w1at + (size_t)d * (MM * 2 * HH);
    for (int i = t; i < MM * 2 * HH; i += 256) W[i] = Wg[i];
  }
  if (t < 128) {
    wb[t] = w1b[(size_t)t * DD + d];
    ba[t] = b1a[(size_t)d * 128 + t];
  }
  {
    int b = t >> 2, c = t & 3;
    const size_t pb = (size_t)b * DD * MM + (size_t)d * MM;
    float sv = g_state[b * DD + d];
#pragma unroll
    for (int mm2 = c * 8; mm2 < c * 8 + 8; ++mm2)
      st[b][mm2] = (mm2 < MM - 1) ? pre[pb + mm2 + 1] : sv;   // [pre[...,1:], state]
  }
  __syncthreads();
  const int wave = t >> 6, lane = t & 63;
  const float g_ln = lng[lane], b_ln = lnb[lane];
  const float wb0 = wb[2 * lane], wb1 = wb[2 * lane + 1];
  const float baa = ba[lane], bag = ba[64 + lane];
  const float bb0 = b1b[2 * d], bb1 = b1b[2 * d + 1];
  for (int b = wave; b < BB; b += 4) {
    float a = baa, g = bag;
#pragma unroll
    for (int m = 0; m < MM; ++m) {
      float s = st[b][m];
      a = fmaf(s, W[m * 128 + lane], a);
      g = fmaf(s, W[m * 128 + 64 + lane], g);
    }
    float hg = a * sigmoidf_(g);
    float mu = wave_sum(hg) * (1.f / 64.f);
    float dv = hg - mu;
    float var = wave_sum(dv * dv) * (1.f / 64.f);
    float hn = dv * rsqrtf(var + 1e-5f) * g_ln + b_ln;
    float o0 = wave_sum(hn * wb0) + bb0;
    float o1 = wave_sum(hn * wb1) + bb1;
    if (lane == 0) g_act[b * DD + d] = o0 * sigmoidf_(o1);
  }
}

// ---------------- K4: r partials (sum, sumsq per row-block) ----------------
__global__ __launch_bounds__(256) void k_r(
    const float* __restrict__ alpha, const float* __restrict__ beta,
    const float* __restrict__ dp) {
  const int b   = blockIdx.x >> 6;
  const int blk = blockIdx.x & 63;
  const float* arow = g_act + b * DD;
  const size_t rowbase = (size_t)b * DSQ;
  float s = 0.f, ss = 0.f;
#pragma unroll
  for (int it = 0; it < 2; ++it) {
    const int off = blk * 4096 + it * 2048 + threadIdx.x * 8;
    const float4 a0 = *(const float4*)(alpha + rowbase + off);
    const float4 a1 = *(const float4*)(alpha + rowbase + off + 4);
    const float4 be0 = *(const float4*)(beta + rowbase + off);
    const float4 be1 = *(const float4*)(beta + rowbase + off + 4);
    const float4 p0 = *(const float4*)(dp + off);
    const float4 p1 = *(const float4*)(dp + off + 4);
    const float ai = arow[off >> 9];
    const int j = off & 511;
    const float4 aj0 = *(const float4*)(arow + j);
    const float4 aj1 = *(const float4*)(arow + j + 4);
    float av[8]  = {a0.x, a0.y, a0.z, a0.w, a1.x, a1.y, a1.z, a1.w};
    float bv[8]  = {be0.x, be0.y, be0.z, be0.w, be1.x, be1.y, be1.z, be1.w};
    float pv[8]  = {p0.x, p0.y, p0.z, p0.w, p1.x, p1.y, p1.z, p1.w};
    float ajv[8] = {aj0.x, aj0.y, aj0.z, aj0.w, aj1.x, aj1.y, aj1.z, aj1.w};
#pragma unroll
    for (int e = 0; e < 8; ++e) {
      float r = r_elem(pv[e], av[e], bv[e], ai * ajv[e]);
      s += r;
      ss = fmaf(r, r, ss);
    }
  }
  s = wave_sum(s); ss = wave_sum(ss);
  __shared__ float rs[4], rss[4];
  int wave = threadIdx.x >> 6, lane = threadIdx.x & 63;
  if (lane == 0) { rs[wave] = s; rss[wave] = ss; }
  __syncthreads();
  if (threadIdx.x == 0) {
    g_part[(b * 64 + blk) * 2]     = rs[0] + rs[1] + rs[2] + rs[3];
    g_part[(b * 64 + blk) * 2 + 1] = rss[0] + rss[1] + rss[2] + rss[3];
  }
}

// ------- K6: reduce partials, recompute r, normalize, write fp32 -------
__global__ __launch_bounds__(256) void k_out(
    const float* __restrict__ alpha, const float* __restrict__ beta,
    const float* __restrict__ dp, const float* __restrict__ g,
    const float* __restrict__ bn, float* __restrict__ out) {
  const int b   = blockIdx.x >> 6;
  const int blk = blockIdx.x & 63;
  __shared__ float sm[2];
  {
    const int t = threadIdx.x;
    if (t < 64) {
      float s  = g_part[(b * 64 + t) * 2];
      float ss = g_part[(b * 64 + t) * 2 + 1];
      s = wave_sum(s); ss = wave_sum(ss);
      if (t == 0) {
        float mean = s * (1.f / (float)DSQ);
        float var  = ss * (1.f / (float)DSQ) - mean * mean;
        sm[0] = mean;
        sm[1] = rsqrtf(fmaxf(var, 0.f) + 1e-5f);
      }
    }
  }
  __syncthreads();
  const float mean = sm[0];
  const float rstd = sm[1];
  const float* arow = g_act + b * DD;
  const size_t rowbase = (size_t)b * DSQ;
#pragma unroll
  for (int it = 0; it < 2; ++it) {
    const int off = blk * 4096 + it * 2048 + threadIdx.x * 8;
    const float4 a0 = *(const float4*)(alpha + rowbase + off);
    const float4 a1 = *(const float4*)(alpha + rowbase + off + 4);
    const float4 be0 = *(const float4*)(beta + rowbase + off);
    const float4 be1 = *(const float4*)(beta + rowbase + off + 4);
    const float4 p0 = *(const float4*)(dp + off);
    const float4 p1 = *(const float4*)(dp + off + 4);
    const float4 g0 = *(const float4*)(g + off);
    const float4 g1 = *(const float4*)(g + off + 4);
    const float4 n0 = *(const float4*)(bn + off);
    const float4 n1 = *(const float4*)(bn + off + 4);
    const float ai = arow[off >> 9];
    const int j = off & 511;
    const float4 aj0 = *(const float4*)(arow + j);
    const float4 aj1 = *(const float4*)(arow + j + 4);
    float av[8]  = {a0.x, a0.y, a0.z, a0.w, a1.x, a1.y, a1.z, a1.w};
    float bv[8]  = {be0.x, be0.y, be0.z, be0.w, be1.x, be1.y, be1.z, be1.w};
    float pv[8]  = {p0.x, p0.y, p0.z, p0.w, p1.x, p1.y, p1.z, p1.w};
    float gv[8]  = {g0.x, g0.y, g0.z, g0.w, g1.x, g1.y, g1.z, g1.w};
    float nv[8]  = {n0.x, n0.y, n0.z, n0.w, n1.x, n1.y, n1.z, n1.w};
    float ajv[8] = {aj0.x, aj0.y, aj0.z, aj0.w, aj1.x, aj1.y, aj1.z, aj1.w};
    float v[8];
#pragma unroll
    for (int e = 0; e < 8; ++e) {
      float r = r_elem(pv[e], av[e], bv[e], ai * ajv[e]);
      v[e] = (r - mean) * rstd * gv[e] + nv[e];
    }
    float4 o0 = make_float4(v[0], v[1], v[2], v[3]);
    float4 o1 = make_float4(v[4], v[5], v[6], v[7]);
    *(float4*)(out + rowbase + off)     = o0;
    *(float4*)(out + rowbase + off + 4) = o1;
  }
}

extern "C" void kernel_launch(void* const* d_in, const int* in_sizes, int n_in,
                              void* d_out, int out_size, void* d_ws, size_t ws_size,
                              hipStream_t stream) {
  const float* x      = (const float*)d_in[0];
  const float* pre    = (const float*)d_in[1];
  const float* post   = (const float*)d_in[2];
  const float* dalpha = (const float*)d_in[3];
  const float* dbeta  = (const float*)d_in[4];
  const float* Wp     = (const float*)d_in[5];
  const float* bp     = (const float*)d_in[6];
  const float* wfix   = (const float*)d_in[7];
  const float* lnsg   = (const float*)d_in[8];
  const float* lnsb   = (const float*)d_in[9];
  const float* w1a    = (const float*)d_in[10];
  const float* b1a    = (const float*)d_in[11];
  const float* lnng   = (const float*)d_in[12];
  const float* lnnb   = (const float*)d_in[13];
  const float* w1b    = (const float*)d_in[14];
  const float* b1b    = (const float*)d_in[15];
  const float* dparam = (const float*)d_in[16];
  const float* lncg   = (const float*)d_in[17];
  const float* lncb   = (const float*)d_in[18];
  float* out = (float*)d_out;                           // fp32 output

  k_wfnorm<<<64, 256, 0, stream>>>(wfix);
  k_transpose<<<dim3(16, 128), 256, 0, stream>>>(w1a);
  k_state<<<64, 512, 0, stream>>>(x, post, Wp, bp, wfix, lnsg, lnsb);
  k_act<<<512, 256, 0, stream>>>(pre, b1a, lnng, lnnb, w1b, b1b);
  k_r<<<4096, 256, 0, stream>>>(dalpha, dbeta, dparam);
  k_out<<<4096, 256, 0, stream>>>(dalpha, dbeta, dparam, lncg, lncb, out);
}

// Round 5
// 289.629 us; speedup vs baseline: 1.3276x; 1.3276x over previous
//
#include <hip/hip_runtime.h>
#include <hip/hip_bf16.h>

#define BB 64
#define DD 512
#define DINN 512
#define MM 32
#define HH 64
#define DSQ (DD*DD)

typedef unsigned short u16;
typedef unsigned int u32;

// ---------------- persistent device scratch (no d_ws dependence) ----------------
__device__ float g_state[BB * DD];
__device__ float g_act[BB * DD];
__device__ float g_y[BB * DD];
__device__ float g_t[BB * DD];
__device__ float g_wnt[DD * DD];                     // Wfix^T (1 MB)
__device__ float g_w1at[(size_t)MM * 2 * HH * DD];   // 8 MB fp32 transposed w1a
__device__ float g_part[BB * 64 * 2];                // per (row, blk) partial sum/sumsq
__device__ float g_wfpart[256];                      // per-block partial ||Wfix||^2
__device__ u16   g_rbf[(size_t)BB * DSQ];            // 33.5 MB bf16-staged r

// ---------------- helpers ----------------
__device__ __forceinline__ float wave_sum(float v) {
#pragma unroll
  for (int m = 32; m; m >>= 1) v += __shfl_xor(v, m);
  return v;
}
__device__ __forceinline__ float sigmoidf_(float x) {
  return 1.f / (1.f + __expf(-x));
}
__device__ __forceinline__ float bf2f(u32 u) { return __uint_as_float(u << 16); }
__device__ __forceinline__ u16 f2bf(float v) {
  __hip_bfloat16 h = __float2bfloat16(v);   // RNE
  return *reinterpret_cast<u16*>(&h);
}
__device__ __forceinline__ u32 pack2(float a, float b) {
  return (u32)f2bf(a) | ((u32)f2bf(b) << 16);
}
__device__ __forceinline__ float r_elem(float p, float al, float be, float pw) {
  float c  = fminf(fmaxf(p, 0.f), 15.f);
  float w2 = __expf(-2.f * c);           // dw^2 = exp(-clip)^2
  return (w2 * al + pw) * rsqrtf(w2 * be + 1.f);
}

// ------- K_twf: transpose Wfix (512x512) -> g_wnt, + ||Wfix||^2 partials -------
__global__ __launch_bounds__(256) void k_twf(const float* __restrict__ Wfix) {
  __shared__ float tile[32][33];
  int c0 = blockIdx.x * 32;          // d (col of Wfix)
  int r0 = blockIdx.y * 32;          // k (row of Wfix)
  int tx = threadIdx.x & 31, ty = threadIdx.x >> 5;   // 32 x 8
  float s = 0.f;
#pragma unroll
  for (int i = 0; i < 32; i += 8) {
    float v = Wfix[(size_t)(r0 + ty + i) * DD + c0 + tx];
    tile[ty + i][tx] = v;
    s = fmaf(v, v, s);
  }
  __syncthreads();
#pragma unroll
  for (int i = 0; i < 32; i += 8)
    g_wnt[(size_t)(c0 + ty + i) * DD + r0 + tx] = tile[tx][ty + i];
  s = wave_sum(s);
  __shared__ float red[4];
  int wv = threadIdx.x >> 6, ln = threadIdx.x & 63;
  if (ln == 0) red[wv] = s;
  __syncthreads();
  if (threadIdx.x == 0)
    g_wfpart[blockIdx.y * 16 + blockIdx.x] = red[0] + red[1] + red[2] + red[3];
}

// ------- K_t1: transpose w1a (4096 x 512) -> g_w1at (512 x 4096) -------
__global__ __launch_bounds__(256) void k_transpose(const float* __restrict__ A) {
  __shared__ float tile[32][33];
  int c0 = blockIdx.x * 32;          // d
  int r0 = blockIdx.y * 32;          // m*128+l
  int tx = threadIdx.x & 31, ty = threadIdx.x >> 5;   // 32 x 8
#pragma unroll
  for (int i = 0; i < 32; i += 8)
    tile[ty + i][tx] = A[(size_t)(r0 + ty + i) * DD + c0 + tx];
  __syncthreads();
#pragma unroll
  for (int i = 0; i < 32; i += 8)
    g_w1at[(size_t)(c0 + ty + i) * 4096 + r0 + tx] = tile[tx][ty + i];
}

// ---- K_y: y[b][d] = inp[b] . Wp[d] + bp[d]; wave-split-K, coalesced Wp reads ----
__global__ __launch_bounds__(256) void k_y(
    const float* __restrict__ x, const float* __restrict__ post,
    const float* __restrict__ Wp, const float* __restrict__ bp) {
  __shared__ __align__(16) float inp[DINN + DD];
  const int b = blockIdx.y;
  const int d0 = blockIdx.x * 64;
  for (int i = threadIdx.x; i < DD; i += 256) {
    inp[i]        = x[(size_t)b * DINN + i];
    inp[DINN + i] = post[((size_t)b * DD + i) * MM + (MM - 1)];
  }
  __syncthreads();
  const int wv = threadIdx.x >> 6, ln = threadIdx.x & 63;
  const float4* i4 = (const float4*)inp;
#pragma unroll 4
  for (int j = 0; j < 16; ++j) {
    const int d = d0 + wv * 16 + j;
    const float4* wr = (const float4*)(Wp + (size_t)d * (DINN + DD));
    float a = 0.f;
#pragma unroll
    for (int it = 0; it < 4; ++it) {
      float4 w = wr[it * 64 + ln];
      float4 iv = i4[it * 64 + ln];
      a = fmaf(iv.x, w.x, a); a = fmaf(iv.y, w.y, a);
      a = fmaf(iv.z, w.z, a); a = fmaf(iv.w, w.w, a);
    }
    a = wave_sum(a);
    if (ln == 0) g_y[b * DD + d] = a + bp[d];
  }
}

// ---- K_t2: t[b][d] = (y[b] . wnT[d]) * rsqrt(wf2); wave-split-K ----
__global__ __launch_bounds__(256) void k_t(const float* __restrict__ dummy) {
  __shared__ __align__(16) float yld[DD];
  __shared__ float red[4];
  __shared__ float wf2s;
  const int b = blockIdx.y;
  const int d0 = blockIdx.x * 64;
  for (int i = threadIdx.x; i < DD; i += 256) yld[i] = g_y[b * DD + i];
  {
    float w = g_wfpart[threadIdx.x];
    w = wave_sum(w);
    int wv = threadIdx.x >> 6, ln = threadIdx.x & 63;
    if (ln == 0) red[wv] = w;
    __syncthreads();
    if (threadIdx.x == 0) wf2s = red[0] + red[1] + red[2] + red[3];
    __syncthreads();
  }
  const float scale = rsqrtf(wf2s);
  const int wv = threadIdx.x >> 6, ln = threadIdx.x & 63;
  const float4* y4 = (const float4*)yld;
#pragma unroll 4
  for (int j = 0; j < 16; ++j) {
    const int d = d0 + wv * 16 + j;
    const float4* wr = (const float4*)(g_wnt + (size_t)d * DD);
    float a = 0.f;
#pragma unroll
    for (int it = 0; it < 2; ++it) {
      float4 w = wr[it * 64 + ln];
      float4 yv = y4[it * 64 + ln];
      a = fmaf(yv.x, w.x, a); a = fmaf(yv.y, w.y, a);
      a = fmaf(yv.z, w.z, a); a = fmaf(yv.w, w.w, a);
    }
    a = wave_sum(a);
    if (ln == 0) g_t[b * DD + d] = a * scale;
  }
}

// ---- K_ln: state = LN_D(t) ----
__global__ __launch_bounds__(512) void k_ln(const float* __restrict__ lng,
                                            const float* __restrict__ lnb) {
  __shared__ float red[16];
  const int b = blockIdx.x;
  const int t = threadIdx.x;
  float tv = g_t[b * DD + t];
  int wave = t >> 6, lane = t & 63;
  float v = wave_sum(tv);
  if (lane == 0) red[wave] = v;
  __syncthreads();
  float tot = 0.f;
#pragma unroll
  for (int i = 0; i < 8; ++i) tot += red[i];
  float mu = tot * (1.f / 512.f);
  float dv = tv - mu;
  float v2 = wave_sum(dv * dv);
  if (lane == 0) red[8 + wave] = v2;
  __syncthreads();
  float tot2 = 0.f;
#pragma unroll
  for (int i = 0; i < 8; ++i) tot2 += red[8 + i];
  float rstd = rsqrtf(tot2 * (1.f / 512.f) + 1e-5f);
  g_state[b * DD + t] = dv * rstd * lng[t] + lnb[t];
}

// ---- K_act: h einsum + GLU + LN(H) + o einsum + GLU -> g_act ----
__global__ __launch_bounds__(256) void k_act(
    const float* __restrict__ pre, const float* __restrict__ b1a,
    const float* __restrict__ lng, const float* __restrict__ lnb,
    const float* __restrict__ w1b, const float* __restrict__ b1b) {
  __shared__ float W[MM * 2 * HH];      // [m][l]  (32 x 128)
  __shared__ float st[BB][MM + 1];
  __shared__ float wb[2 * HH];
  __shared__ float ba[2 * HH];
  const int d = blockIdx.x;
  const int t = threadIdx.x;
  {
    const float* Wg = g_w1at + (size_t)d * (MM * 2 * HH);
    for (int i = t; i < MM * 2 * HH; i += 256) W[i] = Wg[i];
  }
  if (t < 128) {
    wb[t] = w1b[(size_t)t * DD + d];
    ba[t] = b1a[(size_t)d * 128 + t];
  }
  {
    int b = t >> 2, c = t & 3;
    const size_t pb = (size_t)b * DD * MM + (size_t)d * MM;
    float sv = g_state[b * DD + d];
#pragma unroll
    for (int mm2 = c * 8; mm2 < c * 8 + 8; ++mm2)
      st[b][mm2] = (mm2 < MM - 1) ? pre[pb + mm2 + 1] : sv;   // [pre[...,1:], state]
  }
  __syncthreads();
  const int wave = t >> 6, lane = t & 63;
  const float g_ln = lng[lane], b_ln = lnb[lane];
  const float wb0 = wb[2 * lane], wb1 = wb[2 * lane + 1];
  const float baa = ba[lane], bag = ba[64 + lane];
  const float bb0 = b1b[2 * d], bb1 = b1b[2 * d + 1];
  for (int b = wave; b < BB; b += 4) {
    float a = baa, g = bag;
#pragma unroll
    for (int m = 0; m < MM; ++m) {
      float s = st[b][m];
      a = fmaf(s, W[m * 128 + lane], a);
      g = fmaf(s, W[m * 128 + 64 + lane], g);
    }
    float hg = a * sigmoidf_(g);
    float mu = wave_sum(hg) * (1.f / 64.f);
    float dv = hg - mu;
    float var = wave_sum(dv * dv) * (1.f / 64.f);
    float hn = dv * rsqrtf(var + 1e-5f) * g_ln + b_ln;
    float o0 = wave_sum(hn * wb0) + bb0;
    float o1 = wave_sum(hn * wb1) + bb1;
    if (lane == 0) g_act[b * DD + d] = o0 * sigmoidf_(o1);
  }
}

// ---- K_r: compute r, stage as bf16, emit per-block partial sum/sumsq ----
__global__ __launch_bounds__(256) void k_r(
    const float* __restrict__ alpha, const float* __restrict__ beta,
    const float* __restrict__ dp) {
  const int b   = blockIdx.x >> 6;
  const int blk = blockIdx.x & 63;
  const float* arow = g_act + b * DD;
  const size_t rowbase = (size_t)b * DSQ;
  float s = 0.f, ss = 0.f;
#pragma unroll
  for (int it = 0; it < 2; ++it) {
    const int off = blk * 4096 + it * 2048 + threadIdx.x * 8;
    const float4 a0 = *(const float4*)(alpha + rowbase + off);
    const float4 a1 = *(const float4*)(alpha + rowbase + off + 4);
    const float4 be0 = *(const float4*)(beta + rowbase + off);
    const float4 be1 = *(const float4*)(beta + rowbase + off + 4);
    const float4 p0 = *(const float4*)(dp + off);
    const float4 p1 = *(const float4*)(dp + off + 4);
    const float ai = arow[off >> 9];
    const int j = off & 511;
    const float4 aj0 = *(const float4*)(arow + j);
    const float4 aj1 = *(const float4*)(arow + j + 4);
    float av[8]  = {a0.x, a0.y, a0.z, a0.w, a1.x, a1.y, a1.z, a1.w};
    float bv[8]  = {be0.x, be0.y, be0.z, be0.w, be1.x, be1.y, be1.z, be1.w};
    float pv[8]  = {p0.x, p0.y, p0.z, p0.w, p1.x, p1.y, p1.z, p1.w};
    float ajv[8] = {aj0.x, aj0.y, aj0.z, aj0.w, aj1.x, aj1.y, aj1.z, aj1.w};
    float rv[8];
#pragma unroll
    for (int e = 0; e < 8; ++e) {
      float r = r_elem(pv[e], av[e], bv[e], ai * ajv[e]);
      rv[e] = r;
      s += r;
      ss = fmaf(r, r, ss);
    }
    uint4 pk;
    pk.x = pack2(rv[0], rv[1]);
    pk.y = pack2(rv[2], rv[3]);
    pk.z = pack2(rv[4], rv[5]);
    pk.w = pack2(rv[6], rv[7]);
    *reinterpret_cast<uint4*>(g_rbf + rowbase + off) = pk;
  }
  s = wave_sum(s); ss = wave_sum(ss);
  __shared__ float rs[4], rss[4];
  int wave = threadIdx.x >> 6, lane = threadIdx.x & 63;
  if (lane == 0) { rs[wave] = s; rss[wave] = ss; }
  __syncthreads();
  if (threadIdx.x == 0) {
    g_part[(b * 64 + blk) * 2]     = rs[0] + rs[1] + rs[2] + rs[3];
    g_part[(b * 64 + blk) * 2 + 1] = rss[0] + rss[1] + rss[2] + rss[3];
  }
}

// ---- K_out: reduce partials, normalize staged r, write fp32 ----
__global__ __launch_bounds__(256) void k_out(
    const float* __restrict__ g, const float* __restrict__ bn,
    float* __restrict__ out) {
  const int b   = blockIdx.x >> 6;
  const int blk = blockIdx.x & 63;
  __shared__ float sm[2];
  {
    const int t = threadIdx.x;
    if (t < 64) {
      float s  = g_part[(b * 64 + t) * 2];
      float ss = g_part[(b * 64 + t) * 2 + 1];
      s = wave_sum(s); ss = wave_sum(ss);
      if (t == 0) {
        float mean = s * (1.f / (float)DSQ);
        float var  = ss * (1.f / (float)DSQ) - mean * mean;
        sm[0] = mean;
        sm[1] = rsqrtf(fmaxf(var, 0.f) + 1e-5f);
      }
    }
  }
  __syncthreads();
  const float mean = sm[0];
  const float rstd = sm[1];
  const size_t rowbase = (size_t)b * DSQ;
#pragma unroll
  for (int it = 0; it < 2; ++it) {
    const int off = blk * 4096 + it * 2048 + threadIdx.x * 8;
    const uint4 rp = *(const uint4*)(g_rbf + rowbase + off);
    const float4 g0 = *(const float4*)(g + off);
    const float4 g1 = *(const float4*)(g + off + 4);
    const float4 n0 = *(const float4*)(bn + off);
    const float4 n1 = *(const float4*)(bn + off + 4);
    float rv[8] = {bf2f(rp.x & 0xffff), bf2f(rp.x >> 16),
                   bf2f(rp.y & 0xffff), bf2f(rp.y >> 16),
                   bf2f(rp.z & 0xffff), bf2f(rp.z >> 16),
                   bf2f(rp.w & 0xffff), bf2f(rp.w >> 16)};
    float gv[8] = {g0.x, g0.y, g0.z, g0.w, g1.x, g1.y, g1.z, g1.w};
    float nv[8] = {n0.x, n0.y, n0.z, n0.w, n1.x, n1.y, n1.z, n1.w};
    float v[8];
#pragma unroll
    for (int e = 0; e < 8; ++e)
      v[e] = (rv[e] - mean) * rstd * gv[e] + nv[e];
    *(float4*)(out + rowbase + off)     = make_float4(v[0], v[1], v[2], v[3]);
    *(float4*)(out + rowbase + off + 4) = make_float4(v[4], v[5], v[6], v[7]);
  }
}

extern "C" void kernel_launch(void* const* d_in, const int* in_sizes, int n_in,
                              void* d_out, int out_size, void* d_ws, size_t ws_size,
                              hipStream_t stream) {
  const float* x      = (const float*)d_in[0];
  const float* pre    = (const float*)d_in[1];
  const float* post   = (const float*)d_in[2];
  const float* dalpha = (const float*)d_in[3];
  const float* dbeta  = (const float*)d_in[4];
  const float* Wp     = (const float*)d_in[5];
  const float* bp     = (const float*)d_in[6];
  const float* wfix   = (const float*)d_in[7];
  const float* lnsg   = (const float*)d_in[8];
  const float* lnsb   = (const float*)d_in[9];
  const float* w1a    = (const float*)d_in[10];
  const float* b1a    = (const float*)d_in[11];
  const float* lnng   = (const float*)d_in[12];
  const float* lnnb   = (const float*)d_in[13];
  const float* w1b    = (const float*)d_in[14];
  const float* b1b    = (const float*)d_in[15];
  const float* dparam = (const float*)d_in[16];
  const float* lncg   = (const float*)d_in[17];
  const float* lncb   = (const float*)d_in[18];
  float* out = (float*)d_out;                           // fp32 output

  k_twf<<<dim3(16, 16), 256, 0, stream>>>(wfix);
  k_y<<<dim3(8, 64), 256, 0, stream>>>(x, post, Wp, bp);
  k_t<<<dim3(8, 64), 256, 0, stream>>>(nullptr);
  k_ln<<<64, 512, 0, stream>>>(lnsg, lnsb);
  k_transpose<<<dim3(16, 128), 256, 0, stream>>>(w1a);
  k_act<<<512, 256, 0, stream>>>(pre, b1a, lnng, lnnb, w1b, b1b);
  k_r<<<4096, 256, 0, stream>>>(dalpha, dbeta, dparam);
  k_out<<<4096, 256, 0, stream>>>(lncg, lncb, out);
}